// Round 2
// baseline (409.384 us; speedup 1.0000x reference)
//
#include <hip/hip_runtime.h>
#include <cstdint>
#include <cstddef>

#define BB 32
#define NN 1024
#define CIN 128
#define FF 64
#define NOUT 10
#define CAP 128
#define EPSV 1e-5f

// ---------------- fused front: [0,8192) CSR, [8192,10240) x@W0 gemm, [10240] gmax seed ----
// (unchanged from R1 — proven). CSR N-trim + gemm block trim + analytic relu(b2) gmax seed.
__global__ __launch_bounds__(256) void k_front(const float* __restrict__ A,
                                               const float* __restrict__ x,
                                               const float* __restrict__ W0,
                                               const int* __restrict__ Nn,
                                               const float* __restrict__ b2f,
                                               float* __restrict__ gmax,
                                               unsigned short* __restrict__ adj,
                                               int* __restrict__ cnt,
                                               float* __restrict__ c1,
                                               float* __restrict__ c2,
                                               float* __restrict__ T) {
    __shared__ __align__(16) float Wl[64 * 64];    // 16 KB
    int tid = threadIdx.x;
    int wave = tid >> 6, lane = tid & 63;
    if (blockIdx.x >= 10240) {
        for (int i = tid; i < BB * 64; i += 256)
            gmax[i] = fmaxf(b2f[i & 63], 0.f);
        return;
    }
    if (blockIdx.x >= 8192) {
        int gid = blockIdx.x - 8192;        // 8192%8==0 -> XCD gid%8 == b%8, matches spmm
        int b = gid & 31;
        int cch = gid >> 5;                 // chunk in [0,64)
        if (cch * 16 >= Nn[b]) return;      // all 16 rows dead
        int row0 = (b << 10) + cch * 16;
        int rsub = lane >> 4, f0 = (lane & 15) * 4;
        int r = row0 + wave * 4 + rsub;
        const float4* xr = (const float4*)(x + (size_t)r * CIN);
        float4 acc = {0.f, 0.f, 0.f, 0.f};
#pragma unroll
        for (int kc = 0; kc < 2; ++kc) {    // two 64-k chunks of W0
            if (kc) __syncthreads();        // drain prev-chunk readers
            for (int t = tid; t < 64 * 16; t += 256)
                ((float4*)Wl)[t] = ((const float4*)W0)[kc * 1024 + t];
            __syncthreads();
#pragma unroll 4
            for (int k4 = 0; k4 < 16; ++k4) {
                float4 xv = xr[kc * 16 + k4];             // broadcast within 16-lane group
                float4 w0 = *(const float4*)&Wl[(k4 * 4 + 0) * 64 + f0];
                float4 w1 = *(const float4*)&Wl[(k4 * 4 + 1) * 64 + f0];
                float4 w2 = *(const float4*)&Wl[(k4 * 4 + 2) * 64 + f0];
                float4 w3 = *(const float4*)&Wl[(k4 * 4 + 3) * 64 + f0];
                acc.x += xv.x * w0.x; acc.y += xv.x * w0.y; acc.z += xv.x * w0.z; acc.w += xv.x * w0.w;
                acc.x += xv.y * w1.x; acc.y += xv.y * w1.y; acc.z += xv.y * w1.z; acc.w += xv.y * w1.w;
                acc.x += xv.z * w2.x; acc.y += xv.z * w2.y; acc.z += xv.z * w2.z; acc.w += xv.z * w2.w;
                acc.x += xv.w * w3.x; acc.y += xv.w * w3.y; acc.z += xv.w * w3.z; acc.w += xv.w * w3.w;
            }
        }
        *(float4*)&T[(size_t)r * 64 + f0] = acc;
    } else {
        int r = blockIdx.x * 4 + wave;                 // global row in [0, B*N)
        int b = r >> 10;
        int Nb = Nn[b];
        int rl = r & 1023;
        if (rl >= Nb) {
            if (lane == 0) {
                cnt[r] = 0;
                float D = 1.0f / sqrtf(1.0f + EPSV);
                c1[r] = D;
                c2[r] = D * D;
            }
            return;   // per-wave uniform; CSR path has no block-wide sync
        }
        unsigned short* adjs = ((unsigned short*)Wl) + wave * CAP;   // 256 B per wave
        const float4* Arow = (const float4*)(A + (size_t)r * NN);
        int nch = (Nb + 255) >> 8;          // in {2,3,4}
        float4 z4 = {0.f, 0.f, 0.f, 0.f};
        float4 v0 = Arow[lane];
        float4 v1 = Arow[64 + lane];
        float4 v2 = (nch > 2) ? Arow[128 + lane] : z4;
        float4 v3 = (nch > 3) ? Arow[192 + lane] : z4;
        int c = 0;
        unsigned long long lt = (lane == 0) ? 0ULL : ((1ULL << lane) - 1ULL);
        float4 vv[4] = {v0, v1, v2, v3};
#pragma unroll
        for (int it = 0; it < 4; ++it) {
            float4 v = vv[it];
            int j0 = it * 256 + lane * 4;
            unsigned long long m0 = __ballot(v.x != 0.f);
            unsigned long long m1 = __ballot(v.y != 0.f);
            unsigned long long m2 = __ballot(v.z != 0.f);
            unsigned long long m3 = __ballot(v.w != 0.f);
            int before = __popcll(m0 & lt) + __popcll(m1 & lt) +
                         __popcll(m2 & lt) + __popcll(m3 & lt);
            int p = c + before;
            if (v.x != 0.f) { if (p < CAP) adjs[p] = (unsigned short)(j0 + 0); ++p; }
            if (v.y != 0.f) { if (p < CAP) adjs[p] = (unsigned short)(j0 + 1); ++p; }
            if (v.z != 0.f) { if (p < CAP) adjs[p] = (unsigned short)(j0 + 2); ++p; }
            if (v.w != 0.f) { if (p < CAP) adjs[p] = (unsigned short)(j0 + 3); ++p; }
            c += __popcll(m0) + __popcll(m1) + __popcll(m2) + __popcll(m3);
        }
        int cc = (c > CAP) ? CAP : c;
        uint32_t* dst = (uint32_t*)(adj + (size_t)r * CAP);
        if (lane * 2 < cc) dst[lane] = ((const uint32_t*)adjs)[lane];
        if (lane == 0) {
            cnt[r] = cc;
            float D = 1.0f / sqrtf((float)c + 1.0f + EPSV);
            c1[r] = D;
            c2[r] = D * D;
        }
    }
}

// ---------------- layer-1 SpMM + relu + pool score + FUSED next-layer gemm tail ----------
// o (row output) lives in registers only (X never materialized). Tail computes
// Tout[r,f] = sum_k o_k * Wn[k*64+f] via readlane broadcast, ascending-k fma chain —
// bit-identical to the old k_mid gemm (which read the stored o back). Wn from global
// (16 KB, L1-resident after first row).
__global__ __launch_bounds__(256) void k_spmm1(const unsigned short* __restrict__ adj,
                                               const int* __restrict__ cnt,
                                               const float* __restrict__ c1,
                                               const float* __restrict__ c2,
                                               const float* __restrict__ T,
                                               const float* __restrict__ bias,
                                               const float* __restrict__ p,
                                               float* __restrict__ y,
                                               const float* __restrict__ Wn,
                                               float* __restrict__ Tout,
                                               const int* __restrict__ Nn) {
    __shared__ __align__(16) float c1s[NN];
    int b   = blockIdx.x & 31;            // graph
    int cch = blockIdx.x >> 5;            // chunk in [0,64)
    int Nb = Nn[b];
    if (cch * 16 >= Nb) return;
    int tid = threadIdx.x;
    int n4 = (Nb + 3) >> 2;
    if (tid < n4) ((float4*)c1s)[tid] = ((const float4*)(c1 + (b << 10)))[tid];
    __syncthreads();
    int wave = tid >> 6, lane = tid & 63;
    int r0 = (b << 10) + cch * 16 + wave * 4;
    const float* Tb = T + ((size_t)(b << 10) << 6);
    float bv = bias[lane];
    float pv = p[lane];
    float pp = pv * pv;
    for (int s = 32; s; s >>= 1) pp += __shfl_xor(pp, s, 64);
    float ppinv = 1.0f / sqrtf(pp);
#pragma unroll
    for (int rr = 0; rr < 4; ++rr) {
        int r = r0 + rr;
        int rl = r & 1023;
        if (rl >= Nb) break;              // wave-uniform
        const unsigned short* arow = adj + (size_t)r * CAP;
        int n = cnt[r];
        float acc0 = 0.f, acc1 = 0.f, acc2 = 0.f, acc3 = 0.f;
        int t = 0;
        for (; t + 4 <= n; t += 4) {
            ushort4 j4 = *(const ushort4*)(arow + t);
            acc0 += c1s[j4.x] * Tb[((int)j4.x << 6) + lane];
            acc1 += c1s[j4.y] * Tb[((int)j4.y << 6) + lane];
            acc2 += c1s[j4.z] * Tb[((int)j4.z << 6) + lane];
            acc3 += c1s[j4.w] * Tb[((int)j4.w << 6) + lane];
        }
        for (; t < n; ++t) {
            int j = arow[t];
            acc0 += c1s[j] * Tb[(j << 6) + lane];
        }
        float acc = (acc0 + acc1) + (acc2 + acc3);
        float o = c1s[rl] * acc + c2[r] * T[((size_t)r << 6) + lane] + bv;
        o = fmaxf(o, 0.f);
        {   // pool score
            float a = o * pv;
            for (int s = 32; s; s >>= 1) a += __shfl_xor(a, s, 64);
            if (lane == 0) y[r] = a * ppinv;
        }
        {   // fused next-layer gemm: ascending-k fma chain (matches old k_mid order)
            float tac = 0.f;
#pragma unroll 16
            for (int k = 0; k < 64; ++k)
                tac = fmaf(__shfl(o, k, 64), Wn[(k << 6) + lane], tac);
            Tout[((size_t)r << 6) + lane] = tac;
        }
    }
}

// ---------------- fused pool: rank (u64 keys) + masked degree + coeff precompute --------
// One block per graph. Keys (mono(y)<<10)|idx make u64 < equivalent to the stable
// argsort tie-break exactly. nm (0/1) kept in LDS; degree sums are integer-exact in
// f32 -> any order matches. Outputs: nmOut (next pool's mask), ncur, and the spmm
// coefficients csrc[j]=nm*D (== old c1) and scs[j]=tanh(y)*nm (== old per-row sc).
__global__ __launch_bounds__(256) void k_rankdeg(const float* __restrict__ y,
                                                 const float* __restrict__ maskSrc,
                                                 const int* __restrict__ nsrc,
                                                 const int* __restrict__ Nn,
                                                 const unsigned short* __restrict__ adj,
                                                 const int* __restrict__ cnt,
                                                 float* __restrict__ nmOut,
                                                 int* __restrict__ ncur,
                                                 float* __restrict__ csrcO,
                                                 float* __restrict__ scsO) {
    __shared__ __align__(16) float yv[NN];                     // 4 KB
    __shared__ __align__(16) unsigned long long kv[NN];        // 8 KB
    __shared__ float nml[NN];                                  // 4 KB
    int b = blockIdx.x;
    int tid = threadIdx.x;
    const float INF = __builtin_inff();
    int Nb = Nn[b];
    {   // stage masked y
        float4 v;
        if (tid * 4 < Nb) {
            v = ((const float4*)(y + (b << 10)))[tid];
            float4 m = ((const float4*)(maskSrc + (b << 10)))[tid];
            v.x = (m.x > 0.f) ? v.x : INF;
            v.y = (m.y > 0.f) ? v.y : INF;
            v.z = (m.z > 0.f) ? v.z : INF;
            v.w = (m.w > 0.f) ? v.w : INF;
        } else {
            v.x = INF; v.y = INF; v.z = INF; v.w = INF;
        }
        ((float4*)yv)[tid] = v;
    }
    int n = nsrc[b];
    const float RM = (float)(1.0 - 0.8);   // 0.2f, matches jax f32 semantics
    int nrem = (int)((float)n * RM);
    if (tid == 0) ncur[b] = n - nrem;
    __syncthreads();
    // build order keys
#pragma unroll
    for (int t = 0; t < 4; ++t) {
        int i = tid + (t << 8);
        unsigned int u = __float_as_uint(yv[i]);
        u ^= (unsigned int)((int)u >> 31) | 0x80000000u;   // monotone float->uint
        kv[i] = ((unsigned long long)u << 10) | (unsigned int)i;
    }
    __syncthreads();
    // rank: 4 nodes per thread against all keys (uniform-addr LDS broadcast)
    unsigned long long k0 = kv[tid], k1 = kv[tid + 256],
                       k2 = kv[tid + 512], k3 = kv[tid + 768];
    int r0 = 0, r1 = 0, r2 = 0, r3 = 0;
    int nkc = (Nb + 1) >> 1;               // ulonglong2 chunks; tail keys are INF-keys
#pragma unroll 4
    for (int c = 0; c < nkc; ++c) {
        ulonglong2 a = ((const ulonglong2*)kv)[c];
        r0 += (a.x < k0) + (a.y < k0);
        r1 += (a.x < k1) + (a.y < k1);
        r2 += (a.x < k2) + (a.y < k2);
        r3 += (a.x < k3) + (a.y < k3);
    }
    int rk[4] = {r0, r1, r2, r3};
#pragma unroll
    for (int t = 0; t < 4; ++t) {
        int i = tid + (t << 8);
        float nmv = (yv[i] < INF && rk[t] >= nrem) ? 1.f : 0.f;
        nml[i] = nmv;
        nmOut[(b << 10) + i] = nmv;
    }
    __syncthreads();
    // masked degree + coefficients (thread per row; nm gathers from LDS)
#pragma unroll
    for (int t = 0; t < 4; ++t) {
        int i = tid + (t << 8);
        if (i < Nb) {
            int gr = (b << 10) + i;
            float m = nml[i];
            int nn = cnt[gr];
            const unsigned short* ar = adj + (size_t)gr * CAP;
            float s = 0.f;
            int tt = 0;
            for (; tt + 4 <= nn; tt += 4) {
                ushort4 j4 = *(const ushort4*)(ar + tt);
                s += nml[j4.x] + nml[j4.y] + nml[j4.z] + nml[j4.w];
            }
            for (; tt < nn; ++tt) s += nml[ar[tt]];
            float D = 1.0f / sqrtf(m * s + 1.0f + EPSV);
            csrcO[gr] = m * D;
            scsO[gr] = tanhf(yv[i]) * m;
        }
    }
}

// ---------------- layer-2/3 SpMM with deferred scale (+score/gemm-tail or gmax) --------
// Gather term csrc[j]*(scs[j]*T0[j,l]) is bit-identical to old c1s[j]*T[j,l] with
// T = (X@W)*sc (IEEE mul commutative; same rounding points). Self coeff csrc^2 == D^2
// when nm==1 (1.0*D==D); when nm==0 the self term is 0 either way.
__global__ __launch_bounds__(256) void k_spmm23(const unsigned short* __restrict__ adj,
                                                const int* __restrict__ cnt,
                                                const float* __restrict__ csrc,
                                                const float* __restrict__ scs,
                                                const float* __restrict__ Tin,
                                                const float* __restrict__ bias,
                                                const float* __restrict__ p,
                                                float* __restrict__ y,
                                                const float* __restrict__ Wn,
                                                float* __restrict__ Tout,
                                                float* __restrict__ gmax,
                                                const int* __restrict__ Nn) {
    __shared__ __align__(16) float csrcs[NN];
    __shared__ __align__(16) float scss[NN];
    __shared__ float red[4][64];
    int b   = blockIdx.x & 31;
    int cch = blockIdx.x >> 5;
    int Nb = Nn[b];
    if (cch * 16 >= Nb) return;
    int tid = threadIdx.x;
    int n4 = (Nb + 3) >> 2;
    if (tid < n4) {
        ((float4*)csrcs)[tid] = ((const float4*)(csrc + (b << 10)))[tid];
        ((float4*)scss)[tid]  = ((const float4*)(scs  + (b << 10)))[tid];
    }
    __syncthreads();
    int wave = tid >> 6, lane = tid & 63;
    int r0 = (b << 10) + cch * 16 + wave * 4;
    const float* Tb = Tin + ((size_t)(b << 10) << 6);
    float bv = bias[lane];
    float pv = 0.f, ppinv = 0.f;
    if (p != nullptr) {
        pv = p[lane];
        float pp = pv * pv;
        for (int s = 32; s; s >>= 1) pp += __shfl_xor(pp, s, 64);
        ppinv = 1.0f / sqrtf(pp);
    }
    float vmax = 0.f;
#pragma unroll
    for (int rr = 0; rr < 4; ++rr) {
        int r = r0 + rr;
        int rl = r & 1023;
        if (rl >= Nb) break;
        const unsigned short* arow = adj + (size_t)r * CAP;
        int n = cnt[r];
        float acc0 = 0.f, acc1 = 0.f, acc2 = 0.f, acc3 = 0.f;
        int t = 0;
        for (; t + 4 <= n; t += 4) {
            ushort4 j4 = *(const ushort4*)(arow + t);
            acc0 += csrcs[j4.x] * (scss[j4.x] * Tb[((int)j4.x << 6) + lane]);
            acc1 += csrcs[j4.y] * (scss[j4.y] * Tb[((int)j4.y << 6) + lane]);
            acc2 += csrcs[j4.z] * (scss[j4.z] * Tb[((int)j4.z << 6) + lane]);
            acc3 += csrcs[j4.w] * (scss[j4.w] * Tb[((int)j4.w << 6) + lane]);
        }
        for (; t < n; ++t) {
            int j = arow[t];
            acc0 += csrcs[j] * (scss[j] * Tb[(j << 6) + lane]);
        }
        float acc = (acc0 + acc1) + (acc2 + acc3);
        float cd = csrcs[rl];
        float selfv = scss[rl] * Tin[((size_t)r << 6) + lane];
        float o = cd * acc + (cd * cd) * selfv + bv;
        o = fmaxf(o, 0.f);
        if (p != nullptr) {
            float a = o * pv;
            for (int s = 32; s; s >>= 1) a += __shfl_xor(a, s, 64);
            if (lane == 0) y[r] = a * ppinv;
        }
        if (Wn != nullptr) {
            float tac = 0.f;
#pragma unroll 16
            for (int k = 0; k < 64; ++k)
                tac = fmaf(__shfl(o, k, 64), Wn[(k << 6) + lane], tac);
            Tout[((size_t)r << 6) + lane] = tac;
        }
        vmax = fmaxf(vmax, o);
    }
    if (gmax != nullptr) {
        red[wave][lane] = vmax;
        __syncthreads();
        if (wave == 0) {
            float m = fmaxf(fmaxf(red[0][lane], red[1][lane]),
                            fmaxf(red[2][lane], red[3][lane]));
            atomicMax((int*)&gmax[(b << 6) + lane], __float_as_int(m));
        }
    }
}

// ---------------- final fc from the fused global-max buffer ----------------
__global__ __launch_bounds__(64) void k_fc(const float* __restrict__ gmax,
                                           const float* __restrict__ Wfc,
                                           const float* __restrict__ bfc,
                                           float* __restrict__ out) {
    __shared__ float gl[64];
    int b = blockIdx.x, lane = threadIdx.x;
    gl[lane] = gmax[(b << 6) + lane];
    __syncthreads();
    if (lane < NOUT) {
        float acc = bfc[lane];
        for (int k = 0; k < 64; ++k) acc += gl[k] * Wfc[k * NOUT + lane];
        out[b * NOUT + lane] = acc;
    }
}

extern "C" void kernel_launch(void* const* d_in, const int* in_sizes, int n_in,
                              void* d_out, int out_size, void* d_ws, size_t ws_size,
                              hipStream_t stream) {
    const float* x    = (const float*)d_in[0];
    const float* A    = (const float*)d_in[1];
    const float* mask = (const float*)d_in[2];
    const int*   Nn   = (const int*)d_in[3];
    const float* W0   = (const float*)d_in[4];
    const float* b0   = (const float*)d_in[5];
    const float* W1   = (const float*)d_in[6];
    const float* b1   = (const float*)d_in[7];
    const float* W2   = (const float*)d_in[8];
    const float* b2   = (const float*)d_in[9];
    const float* p0   = (const float*)d_in[10];
    const float* p1   = (const float*)d_in[11];
    const float* Wfc  = (const float*)d_in[12];
    const float* bfc  = (const float*)d_in[13];
    float* out = (float*)d_out;

    char* ws = (char*)d_ws;
    size_t off = 0;
    auto alloc = [&](size_t bytes) -> void* {
        void* p = ws + off;
        off = (off + bytes + 255) & ~(size_t)255;
        return p;
    };
    unsigned short* adj = (unsigned short*)alloc((size_t)BB * NN * CAP * 2);
    int*   cnt  = (int*)  alloc((size_t)BB * NN * 4);
    float* X    = (float*)alloc((size_t)BB * NN * 64 * 4);   // layer-2 T0 (o1@W1)
    float* T    = (float*)alloc((size_t)BB * NN * 64 * 4);   // layer-1 T0, then layer-3 T0
    float* c1   = (float*)alloc((size_t)BB * NN * 4);        // also csrc for layers 2/3
    float* c2   = (float*)alloc((size_t)BB * NN * 4);        // also scs  for layers 2/3
    float* y    = (float*)alloc((size_t)BB * NN * 4);
    float* nm0  = (float*)alloc((size_t)BB * NN * 4);
    float* nm1  = (float*)alloc((size_t)BB * NN * 4);
    int*   nc0  = (int*)  alloc((size_t)BB * 4);
    int*   nc1  = (int*)  alloc((size_t)BB * 4);
    float* gmax = (float*)alloc((size_t)BB * 64 * 4);

    // 1) fused: CSR build (8192) + x@W0 gemm (2048) + gmax relu(b2) seed (1 block)
    k_front<<<8192 + 2048 + 1, 256, 0, stream>>>(A, x, W0, Nn, b2, gmax,
                                                 adj, cnt, c1, c2, T);
    // 2) layer-1 SpMM + pool-1 score + fused o1@W1 -> X
    k_spmm1<<<2048, 256, 0, stream>>>(adj, cnt, c1, c2, T, b0, p0, y, W1, X, Nn);
    // 3) pool 1: rank + deg + coeffs (csrc->c1, scs->c2)
    k_rankdeg<<<BB, 256, 0, stream>>>(y, mask, Nn, Nn, adj, cnt, nm0, nc0, c1, c2);
    // 4) layer-2 SpMM (deferred scale) + pool-2 score + fused o2@W2 -> T
    k_spmm23<<<2048, 256, 0, stream>>>(adj, cnt, c1, c2, X, b1, p1, y, W2, T,
                                       nullptr, Nn);
    // 5) pool 2
    k_rankdeg<<<BB, 256, 0, stream>>>(y, nm0, nc0, Nn, adj, cnt, nm1, nc1, c1, c2);
    // 6) layer-3 SpMM (deferred scale) + fused global max
    k_spmm23<<<2048, 256, 0, stream>>>(adj, cnt, c1, c2, T, b2, nullptr, nullptr,
                                       nullptr, nullptr, gmax, Nn);
    // 7) fc from gmax
    k_fc<<<BB, 64, 0, stream>>>(gmax, Wfc, bfc, out);
}

// Round 3
// 355.099 us; speedup vs baseline: 1.1529x; 1.1529x over previous
//
#include <hip/hip_runtime.h>
#include <cstdint>
#include <cstddef>

#define BB 32
#define NN 1024
#define CIN 128
#define FF 64
#define NOUT 10
#define CAP 128
#define EPSV 1e-5f

// non-temporal float4 load: stream-once data (A, x, Xin) must not evict the
// gather-hot T rows from the XCD-local L2.
typedef float vf4 __attribute__((ext_vector_type(4)));
__device__ __forceinline__ float4 ldnt(const float4* p) {
    vf4 v = __builtin_nontemporal_load((const vf4*)p);
    return make_float4(v.x, v.y, v.z, v.w);
}

// ---------------- fused front: [0,8192) CSR, [8192,10240) x@W0 gemm, [10240] gmax seed ----
// R3: A and x loads are non-temporal (stream-once) so the T tile this kernel
// produces stays L2-resident for the spmm gathers that follow.
__global__ __launch_bounds__(256) void k_front(const float* __restrict__ A,
                                               const float* __restrict__ x,
                                               const float* __restrict__ W0,
                                               const int* __restrict__ Nn,
                                               const float* __restrict__ b2f,
                                               float* __restrict__ gmax,
                                               unsigned short* __restrict__ adj,
                                               int* __restrict__ cnt,
                                               float* __restrict__ c1,
                                               float* __restrict__ c2,
                                               float* __restrict__ T) {
    __shared__ __align__(16) float Wl[64 * 64];    // 16 KB
    int tid = threadIdx.x;
    int wave = tid >> 6, lane = tid & 63;
    if (blockIdx.x >= 10240) {
        // gmax seed: relu(b2) per lane, all graphs (exact: every graph has >=102
        // pool-dropped nodes whose layer-3 row is exactly relu(b2))
        for (int i = tid; i < BB * 64; i += 256)
            gmax[i] = fmaxf(b2f[i & 63], 0.f);
        return;
    }
    if (blockIdx.x >= 8192) {
        int gid = blockIdx.x - 8192;        // 8192%8==0 -> XCD gid%8 == b%8, matches spmm
        int b = gid & 31;
        int cch = gid >> 5;                 // chunk in [0,64)
        if (cch * 16 >= Nn[b]) return;      // all 16 rows dead
        int row0 = (b << 10) + cch * 16;
        int rsub = lane >> 4, f0 = (lane & 15) * 4;
        int r = row0 + wave * 4 + rsub;
        const float4* xr = (const float4*)(x + (size_t)r * CIN);
        float4 acc = {0.f, 0.f, 0.f, 0.f};
#pragma unroll
        for (int kc = 0; kc < 2; ++kc) {    // two 64-k chunks of W0
            if (kc) __syncthreads();        // drain prev-chunk readers
            for (int t = tid; t < 64 * 16; t += 256)
                ((float4*)Wl)[t] = ((const float4*)W0)[kc * 1024 + t];   // W0 cached (reused by all blocks)
            __syncthreads();
#pragma unroll 4
            for (int k4 = 0; k4 < 16; ++k4) {
                float4 xv = ldnt(xr + kc * 16 + k4);      // stream-once
                float4 w0 = *(const float4*)&Wl[(k4 * 4 + 0) * 64 + f0];
                float4 w1 = *(const float4*)&Wl[(k4 * 4 + 1) * 64 + f0];
                float4 w2 = *(const float4*)&Wl[(k4 * 4 + 2) * 64 + f0];
                float4 w3 = *(const float4*)&Wl[(k4 * 4 + 3) * 64 + f0];
                acc.x += xv.x * w0.x; acc.y += xv.x * w0.y; acc.z += xv.x * w0.z; acc.w += xv.x * w0.w;
                acc.x += xv.y * w1.x; acc.y += xv.y * w1.y; acc.z += xv.y * w1.z; acc.w += xv.y * w1.w;
                acc.x += xv.z * w2.x; acc.y += xv.z * w2.y; acc.z += xv.z * w2.z; acc.w += xv.z * w2.w;
                acc.x += xv.w * w3.x; acc.y += xv.w * w3.y; acc.z += xv.w * w3.z; acc.w += xv.w * w3.w;
            }
        }
        *(float4*)&T[(size_t)r * 64 + f0] = acc;
    } else {
        int r = blockIdx.x * 4 + wave;                 // global row in [0, B*N)
        int b = r >> 10;
        int Nb = Nn[b];
        int rl = r & 1023;
        if (rl >= Nb) {
            if (lane == 0) {
                cnt[r] = 0;
                float D = 1.0f / sqrtf(1.0f + EPSV);
                c1[r] = D;
                c2[r] = D * D;
            }
            return;   // per-wave uniform; CSR path has no block-wide sync
        }
        unsigned short* adjs = ((unsigned short*)Wl) + wave * CAP;   // 256 B per wave
        const float4* Arow = (const float4*)(A + (size_t)r * NN);
        int nch = (Nb + 255) >> 8;          // in {2,3,4}
        float4 z4 = {0.f, 0.f, 0.f, 0.f};
        float4 v0 = ldnt(Arow + lane);
        float4 v1 = ldnt(Arow + 64 + lane);
        float4 v2 = (nch > 2) ? ldnt(Arow + 128 + lane) : z4;
        float4 v3 = (nch > 3) ? ldnt(Arow + 192 + lane) : z4;
        int c = 0;
        unsigned long long lt = (lane == 0) ? 0ULL : ((1ULL << lane) - 1ULL);
        float4 vv[4] = {v0, v1, v2, v3};
#pragma unroll
        for (int it = 0; it < 4; ++it) {
            float4 v = vv[it];
            int j0 = it * 256 + lane * 4;
            unsigned long long m0 = __ballot(v.x != 0.f);
            unsigned long long m1 = __ballot(v.y != 0.f);
            unsigned long long m2 = __ballot(v.z != 0.f);
            unsigned long long m3 = __ballot(v.w != 0.f);
            int before = __popcll(m0 & lt) + __popcll(m1 & lt) +
                         __popcll(m2 & lt) + __popcll(m3 & lt);
            int p = c + before;
            if (v.x != 0.f) { if (p < CAP) adjs[p] = (unsigned short)(j0 + 0); ++p; }
            if (v.y != 0.f) { if (p < CAP) adjs[p] = (unsigned short)(j0 + 1); ++p; }
            if (v.z != 0.f) { if (p < CAP) adjs[p] = (unsigned short)(j0 + 2); ++p; }
            if (v.w != 0.f) { if (p < CAP) adjs[p] = (unsigned short)(j0 + 3); ++p; }
            c += __popcll(m0) + __popcll(m1) + __popcll(m2) + __popcll(m3);
        }
        int cc = (c > CAP) ? CAP : c;
        uint32_t* dst = (uint32_t*)(adj + (size_t)r * CAP);
        if (lane * 2 < cc) dst[lane] = ((const uint32_t*)adjs)[lane];
        if (lane == 0) {
            cnt[r] = cc;
            float D = 1.0f / sqrtf((float)c + 1.0f + EPSV);
            c1[r] = D;
            c2[r] = D * D;
        }
    }
}

// ---------------- fused mid: [0,8192) = deg, [8192,10240) = gemm64 (scaled) ----------------
// R3: deg waves with nm[r]==0 write c1=0 and skip the gather-sum (c2 unread for
// dead rows since spmm skips them). Xin loads non-temporal (read-once).
__global__ __launch_bounds__(256) void k_mid(const unsigned short* __restrict__ adj,
                                             const int* __restrict__ cnt,
                                             const float* __restrict__ nm,
                                             float* __restrict__ c1, float* __restrict__ c2,
                                             const float* __restrict__ Xin,
                                             const float* __restrict__ W,
                                             const float* __restrict__ y,
                                             float* __restrict__ T,
                                             const int* __restrict__ Nn) {
    __shared__ __align__(16) float Wl[64 * 64];    // 16 KB
    int tid = threadIdx.x;
    if (blockIdx.x >= 8192) {
        // ---- gemm64 with tanh(y)*nm row-scale ----
        int gid = blockIdx.x - 8192;
        int b = gid & 31;                   // XCD matches spmm reader
        int cch = gid >> 5;
        if (cch * 16 >= Nn[b]) return;      // dead 16-row chunk (before any barrier)
        int row0 = (b << 10) + cch * 16;
        for (int t = tid; t < 64 * 16; t += 256)
            ((float4*)Wl)[t] = ((const float4*)W)[t];
        __syncthreads();
        int wave = tid >> 6, lane = tid & 63;
        int rsub = lane >> 4, f0 = (lane & 15) * 4;
        int r = row0 + wave * 4 + rsub;
        float sc = tanhf(y[r]) * nm[r];     // same value across the 16-lane group
        const float4* xr = (const float4*)(Xin + (size_t)r * 64);
        float4 acc = {0.f, 0.f, 0.f, 0.f};
#pragma unroll 4
        for (int k4 = 0; k4 < 16; ++k4) {
            float4 xv = ldnt(xr + k4);      // read-once stream
            float4 w0 = *(const float4*)&Wl[(k4 * 4 + 0) * 64 + f0];
            float4 w1 = *(const float4*)&Wl[(k4 * 4 + 1) * 64 + f0];
            float4 w2 = *(const float4*)&Wl[(k4 * 4 + 2) * 64 + f0];
            float4 w3 = *(const float4*)&Wl[(k4 * 4 + 3) * 64 + f0];
            acc.x += xv.x * w0.x; acc.y += xv.x * w0.y; acc.z += xv.x * w0.z; acc.w += xv.x * w0.w;
            acc.x += xv.y * w1.x; acc.y += xv.y * w1.y; acc.z += xv.y * w1.z; acc.w += xv.y * w1.w;
            acc.x += xv.z * w2.x; acc.y += xv.z * w2.y; acc.z += xv.z * w2.z; acc.w += xv.z * w2.w;
            acc.x += xv.w * w3.x; acc.y += xv.w * w3.y; acc.z += xv.w * w3.z; acc.w += xv.w * w3.w;
        }
        acc.x *= sc; acc.y *= sc; acc.z *= sc; acc.w *= sc;
        *(float4*)&T[(size_t)r * 64 + f0] = acc;
    } else {
        // ---- masked degree, wave per row (nm entries are 0/1 -> order-exact) ----
        int wave = tid >> 6, lane = tid & 63;
        int r = blockIdx.x * 4 + wave;
        int b = r >> 10;
        if ((r & 1023) >= Nn[b]) return;   // dead row: c1/c2 never consumed downstream
        float m = nm[r];
        if (m == 0.f) {                    // pool-dropped: spmm skips this row;
            if (lane == 0) c1[r] = 0.f;    // only the gather coeff (=0) is ever read
            return;
        }
        const unsigned short* arow = adj + (size_t)r * CAP;
        const float* nmb = nm + (b << 10);
        int n = cnt[r];
        float s = 0.f;
        if (lane < n)      s  = nmb[arow[lane]];
        if (lane + 64 < n) s += nmb[arow[lane + 64]];
        for (int sh = 32; sh; sh >>= 1) s += __shfl_xor(s, sh, 64);
        if (lane == 0) {
            float D = 1.0f / sqrtf(m * s + 1.0f + EPSV);
            c1[r] = m * D;                 // m==1 here: == D bitwise
            c2[r] = D * D;
        }
    }
}

// ---------------- SpMM + self + bias + relu (+ pool score OR fused global max) ----------------
// R3: rows with c1s[rl]==0 (pool-dropped, layers 2/3 only) are skipped wave-uniformly:
// their output is exactly relu(bias) -> layer-2 y is INF-masked by rank, layer-3 gmax
// contribution is covered by the analytic relu(b2) seed, and their T input to the next
// layer is multiplied by sc=0. Layer 1 has c1=D>0, never skips.
__global__ __launch_bounds__(256) void k_spmm(const unsigned short* __restrict__ adj,
                                              const int* __restrict__ cnt,
                                              const float* __restrict__ c1,
                                              const float* __restrict__ c2,
                                              const float* __restrict__ T,
                                              const float* __restrict__ bias,
                                              float* __restrict__ X,
                                              const float* __restrict__ p,
                                              float* __restrict__ y,
                                              float* __restrict__ gmax,
                                              const int* __restrict__ Nn) {
    __shared__ __align__(16) float c1s[NN];
    __shared__ float red[4][64];
    int b   = blockIdx.x & 31;            // graph
    int cch = blockIdx.x >> 5;            // chunk in [0,64)
    int Nb = Nn[b];
    if (cch * 16 >= Nb) return;           // all rows dead (uniform, before barrier)
    int tid = threadIdx.x;
    int n4 = (Nb + 3) >> 2;               // stage only the live c1 prefix
    if (tid < n4) ((float4*)c1s)[tid] = ((const float4*)(c1 + (b << 10)))[tid];
    __syncthreads();
    int wave = tid >> 6, lane = tid & 63;
    int r0 = (b << 10) + cch * 16 + wave * 4;
    const float* Tb = T + ((size_t)(b << 10) << 6);
    float bv = bias[lane];
    float pv = 0.f, ppinv = 0.f;
    if (p != nullptr) {
        pv = p[lane];
        float pp = pv * pv;
        for (int s = 32; s; s >>= 1) pp += __shfl_xor(pp, s, 64);
        ppinv = 1.0f / sqrtf(pp);
    }
    float vmax = 0.f;
#pragma unroll
    for (int rr = 0; rr < 4; ++rr) {
        int r = r0 + rr;
        int rl = r & 1023;
        if (rl >= Nb) break;              // boundary chunk: remaining rows dead
        if (c1s[rl] == 0.f) continue;     // pool-dropped row (wave-uniform)
        const unsigned short* arow = adj + (size_t)r * CAP;
        int n = cnt[r];
        float acc0 = 0.f, acc1 = 0.f, acc2 = 0.f, acc3 = 0.f;
        int t = 0;
        for (; t + 4 <= n; t += 4) {
            ushort4 j4 = *(const ushort4*)(arow + t);
            acc0 += c1s[j4.x] * Tb[((int)j4.x << 6) + lane];
            acc1 += c1s[j4.y] * Tb[((int)j4.y << 6) + lane];
            acc2 += c1s[j4.z] * Tb[((int)j4.z << 6) + lane];
            acc3 += c1s[j4.w] * Tb[((int)j4.w << 6) + lane];
        }
        for (; t < n; ++t) {
            int j = arow[t];
            acc0 += c1s[j] * Tb[(j << 6) + lane];
        }
        float acc = (acc0 + acc1) + (acc2 + acc3);
        float o = c1s[rl] * acc + c2[r] * T[((size_t)r << 6) + lane] + bv;
        o = fmaxf(o, 0.f);
        if (X != nullptr) X[((size_t)r << 6) + lane] = o;
        if (p != nullptr) {
            float a = o * pv;
            for (int s = 32; s; s >>= 1) a += __shfl_xor(a, s, 64);
            if (lane == 0) y[r] = a * ppinv;
        }
        vmax = fmaxf(vmax, o);
    }
    if (gmax != nullptr) {
        red[wave][lane] = vmax;
        __syncthreads();
        if (wave == 0) {
            float m = fmaxf(fmaxf(red[0][lane], red[1][lane]),
                            fmaxf(red[2][lane], red[3][lane]));
            // all values >= 0: int compare of float bits preserves order; gmax pre-seeded
            atomicMax((int*)&gmax[(b << 6) + lane], __float_as_int(m));
        }
    }
}

// ---------------- pool ranking: stable-argsort semantics, 16 blocks/graph ----------------
// R3: blocks whose 64-node slice is entirely >= Nb return immediately (their nmOut
// is never read: gemm64/deg/rank only touch nm below the slice containing Nb+14,
// whose 64-block start is provably < Nb).
__global__ __launch_bounds__(256) void k_rank(const float* __restrict__ y,
                                              const float* __restrict__ maskSrc,
                                              const int* __restrict__ nsrc,
                                              const int* __restrict__ nbound,
                                              float* __restrict__ nmOut,
                                              int* __restrict__ ncur) {
    __shared__ __align__(16) float yv[NN];
    int b = blockIdx.x >> 4;       // 16 blocks per graph
    int sub = blockIdx.x & 15;
    int tid = threadIdx.x;
    const float INF = __builtin_inff();
    int Nb = nbound[b];
    if ((sub << 6) >= Nb) return;  // all 64 nodes dead; nm never read there
    {
        float4 v;
        if (tid * 4 < Nb) {
            v = ((const float4*)(y + (b << 10)))[tid];
            float4 m = ((const float4*)(maskSrc + (b << 10)))[tid];
            v.x = (m.x > 0.f) ? v.x : INF;
            v.y = (m.y > 0.f) ? v.y : INF;
            v.z = (m.z > 0.f) ? v.z : INF;
            v.w = (m.w > 0.f) ? v.w : INF;
        } else {
            v.x = INF; v.y = INF; v.z = INF; v.w = INF;
        }
        ((float4*)yv)[tid] = v;
    }
    int n = nsrc[b];
    const float RM = (float)(1.0 - 0.8);   // 0.2f, matches jax f32 semantics
    int nrem = (int)((float)n * RM);
    if (sub == 0 && tid == 0) ncur[b] = n - nrem;
    __syncthreads();
    int i = (sub << 6) + (tid >> 2);       // 64 nodes per block, 4 threads per node
    int q = tid & 3;                       // quarter of the j-range
    float yi = yv[i];
    int rank = 0;
    if (yi < INF) {
        const float4* jbase = (const float4*)yv + (q << 6);
        int j0 = q << 8;
        int tend = (Nb - j0 + 3) >> 2;     // <=0 when the whole quarter is dead
        if (tend > 64) tend = 64;
#pragma unroll 8
        for (int t = 0; t < tend; ++t) {
            float4 a = jbase[t];
            int j = j0 + t * 4;
            rank += (a.x < yi || (a.x == yi && j     < i)) ? 1 : 0;
            rank += (a.y < yi || (a.y == yi && j + 1 < i)) ? 1 : 0;
            rank += (a.z < yi || (a.z == yi && j + 2 < i)) ? 1 : 0;
            rank += (a.w < yi || (a.w == yi && j + 3 < i)) ? 1 : 0;
        }
    }
    rank += __shfl_xor(rank, 1, 64);
    rank += __shfl_xor(rank, 2, 64);
    if (q == 0) {
        float nmv = (yi < INF && rank >= nrem) ? 1.f : 0.f;
        nmOut[(b << 10) + i] = nmv;
    }
}

// ---------------- final fc from the fused global-max buffer ----------------
__global__ __launch_bounds__(64) void k_fc(const float* __restrict__ gmax,
                                           const float* __restrict__ Wfc,
                                           const float* __restrict__ bfc,
                                           float* __restrict__ out) {
    __shared__ float gl[64];
    int b = blockIdx.x, lane = threadIdx.x;
    gl[lane] = gmax[(b << 6) + lane];
    __syncthreads();
    if (lane < NOUT) {
        float acc = bfc[lane];
        for (int k = 0; k < 64; ++k) acc += gl[k] * Wfc[k * NOUT + lane];
        out[b * NOUT + lane] = acc;
    }
}

extern "C" void kernel_launch(void* const* d_in, const int* in_sizes, int n_in,
                              void* d_out, int out_size, void* d_ws, size_t ws_size,
                              hipStream_t stream) {
    const float* x    = (const float*)d_in[0];
    const float* A    = (const float*)d_in[1];
    const float* mask = (const float*)d_in[2];
    const int*   Nn   = (const int*)d_in[3];
    const float* W0   = (const float*)d_in[4];
    const float* b0   = (const float*)d_in[5];
    const float* W1   = (const float*)d_in[6];
    const float* b1   = (const float*)d_in[7];
    const float* W2   = (const float*)d_in[8];
    const float* b2   = (const float*)d_in[9];
    const float* p0   = (const float*)d_in[10];
    const float* p1   = (const float*)d_in[11];
    const float* Wfc  = (const float*)d_in[12];
    const float* bfc  = (const float*)d_in[13];
    float* out = (float*)d_out;

    char* ws = (char*)d_ws;
    size_t off = 0;
    auto alloc = [&](size_t bytes) -> void* {
        void* p = ws + off;
        off = (off + bytes + 255) & ~(size_t)255;
        return p;
    };
    unsigned short* adj = (unsigned short*)alloc((size_t)BB * NN * CAP * 2);
    int*   cnt  = (int*)  alloc((size_t)BB * NN * 4);
    float* X    = (float*)alloc((size_t)BB * NN * 64 * 4);
    float* T    = (float*)alloc((size_t)BB * NN * 64 * 4);
    float* c1   = (float*)alloc((size_t)BB * NN * 4);
    float* c2   = (float*)alloc((size_t)BB * NN * 4);
    float* y    = (float*)alloc((size_t)BB * NN * 4);
    float* nm0  = (float*)alloc((size_t)BB * NN * 4);
    float* nm1  = (float*)alloc((size_t)BB * NN * 4);
    int*   nc0  = (int*)  alloc((size_t)BB * 4);
    int*   nc1  = (int*)  alloc((size_t)BB * 4);
    float* gmax = (float*)alloc((size_t)BB * 64 * 4);

    // 1) fused: CSR build (8192) + x@W0 gemm (2048) + gmax relu(b2) seed (1 block)
    k_front<<<8192 + 2048 + 1, 256, 0, stream>>>(A, x, W0, Nn, b2, gmax,
                                                 adj, cnt, c1, c2, T);
    // 2) layer 1 SpMM (+ pool-1 score)
    k_spmm<<<2048, 256, 0, stream>>>(adj, cnt, c1, c2, T, b0, X, p0, y, nullptr, Nn);
    // pool 1
    k_rank<<<BB * 16, 256, 0, stream>>>(y, mask, Nn, Nn, nm0, nc0);
    // 3) layer 2: fused deg (first) + gemm64
    k_mid<<<8192 + 2048, 256, 0, stream>>>(adj, cnt, nm0, c1, c2, X, W1, y, T, Nn);
    k_spmm<<<2048, 256, 0, stream>>>(adj, cnt, c1, c2, T, b1, X, p1, y, nullptr, Nn);
    // pool 2 (double-buffered mask; count source nc0, index bound stays Nn)
    k_rank<<<BB * 16, 256, 0, stream>>>(y, nm0, nc0, Nn, nm1, nc1);
    // 4) layer 3: fused deg (first) + gemm64; spmm fuses global max (no X write)
    k_mid<<<8192 + 2048, 256, 0, stream>>>(adj, cnt, nm1, c1, c2, X, W2, y, T, Nn);
    k_spmm<<<2048, 256, 0, stream>>>(adj, cnt, c1, c2, T, b2, nullptr, nullptr, nullptr,
                                     gmax, Nn);
    // 5) fc from gmax
    k_fc<<<BB, 64, 0, stream>>>(gmax, Wfc, bfc, out);
}